// Round 1
// baseline (826.575 us; speedup 1.0000x reference)
//
#include <hip/hip_runtime.h>

typedef unsigned int u32;
typedef unsigned long long u64;

#define NIMG 8
#define RR 10000
#define KK 80
#define SROW 81            // scores/logits row stride (K+1)
#define MPRE 2048
#define NTOP 100
#define NELEM (RR*KK)      // 800000 per image
#define BPI 391            // blocks/image for scan kernels: 391*2048 >= 800000
#define HIST_BINS 65536

// ---- workspace layout (bytes) ----
#define OFF_HIST   0ull
#define OFF_STATE  (8ull*HIST_BINS*4ull)              // 2,097,152
#define ST_DONE    0
#define ST_SHIFT   32
#define ST_NEED    64
#define ST_C       96
#define ST_GCNT    128
#define ST_CSEL    160
#define ST_PREFIX  192                                 // u64[8]
#define OFF_SELK   (OFF_STATE + 256)
#define OFF_CB     (OFF_SELK + 8ull*MPRE*8)
#define OFF_OB     (OFF_CB   + 8ull*MPRE*16)
#define OFF_AREA   (OFF_OB   + 8ull*MPRE*16)
#define OFF_SCORE  (OFF_AREA + 8ull*MPRE*4)
#define OFF_FLAT   (OFF_SCORE+ 8ull*MPRE*4)
#define OFF_SUP    (OFF_FLAT + 8ull*MPRE*4)
#define OFF_KEEP   (OFF_SUP  + 8ull*MPRE*32*8)
// total = OFF_KEEP + 2048 = 7,145,728 bytes (~6.8 MB)

// Zero hist + per-image state; need[] initialized to MPRE by the covering thread.
__global__ void k_init(u32* ws32) {
    u32 idx = blockIdx.x * 256u + threadIdx.x;
    u32 nwords = (u32)(OFF_SELK / 4);
    if (idx < nwords) {
        u32 v = 0;
        u32 needbase = (u32)((OFF_STATE + ST_NEED) / 4);
        if (idx >= needbase && idx < needbase + 8) v = MPRE;
        ws32[idx] = v;
    }
}

// 16-bit radix histogram pass p (p=0..3). key = (~score_bits<<32)|flat_idx.
__global__ void k_hist(int p, const float* __restrict__ scores, char* wsb) {
    int img = blockIdx.x / BPI, blk = blockIdx.x % BPI;
    const u32* done = (const u32*)(wsb + OFF_STATE + ST_DONE);
    if (done[img]) return;
    u32 sh = 0; u64 P = 0;
    if (p > 0) {
        sh = ((const u32*)(wsb + OFF_STATE + ST_SHIFT))[img];
        P  = ((const u64*)(wsb + OFF_STATE + ST_PREFIX))[img];
    }
    u32* hist = (u32*)(wsb + OFF_HIST) + (size_t)img * HIST_BINS;
    const float* S = scores + (size_t)img * RR * SROW;
    int binshift = 48 - 16 * p;
    for (int t = 0; t < 8; ++t) {
        int e = blk * 2048 + t * 256 + (int)threadIdx.x;
        if (e < NELEM) {
            int r = e / KK, c = e - r * KK;
            float s = S[(size_t)r * SROW + c];
            if (s > 0.05f) {
                u64 key = ((u64)(~__float_as_uint(s)) << 32) | (u32)e;
                bool m = (p == 0) || ((key >> sh) == P);
                if (m) atomicAdd(&hist[(u32)((key >> binshift) & 0xFFFFull)], 1u);
            }
        }
    }
}

// Per-image bin selection; sets done when selection boundary is a whole bin.
__global__ void k_pick(int p, char* wsb) {
    int img = blockIdx.x; int tid = threadIdx.x;
    u32* done = (u32*)(wsb + OFF_STATE + ST_DONE);
    __shared__ u32 sdone;
    __shared__ u32 chunksum[256];
    if (tid == 0) sdone = done[img];
    __syncthreads();
    if (sdone) return;
    u32* h = (u32*)(wsb + OFF_HIST) + (size_t)img * HIST_BINS;
    u32 cs = 0; int b0 = tid * 256;
    for (int b = 0; b < 256; ++b) cs += h[b0 + b];
    chunksum[tid] = cs;
    __syncthreads();
    if (tid == 0) {
        u32* shiftA = (u32*)(wsb + OFF_STATE + ST_SHIFT);
        u32* needA  = (u32*)(wsb + OFF_STATE + ST_NEED);
        u32* CA     = (u32*)(wsb + OFF_STATE + ST_C);
        u64* prefA  = (u64*)(wsb + OFF_STATE + ST_PREFIX);
        u32 need = needA[img];
        u32 total = 0;
        for (int k2 = 0; k2 < 256; ++k2) total += chunksum[k2];
        bool finished = false;
        if (p == 0) {
            CA[img] = total;
            if (total <= MPRE) {  // fewer than 2048 candidates: take all
                done[img] = 1; shiftA[img] = 0; prefA[img] = ~0ull; finished = true;
            }
        }
        if (!finished) {
            u32 cum = 0; int ck = 0;
            for (int k2 = 0; k2 < 256; ++k2) {
                if (cum + chunksum[k2] >= need) { ck = k2; break; }
                cum += chunksum[k2];
            }
            int bsel = ck * 256; u32 cntb = 0;
            for (int b = ck * 256; b < ck * 256 + 256; ++b) {
                u32 hb = h[b];
                if (cum + hb >= need) { bsel = b; cntb = hb; break; }
                cum += hb;
            }
            need -= cum;                       // rank within chosen bin, 1..cntb
            u64 P = (prefA[img] << 16) | (u32)bsel;
            prefA[img] = P;
            shiftA[img] = (u32)(48 - 16 * p);
            needA[img] = need;
            if (need == cntb || p == 3) done[img] = 1;  // whole bin taken => exact
        }
    }
    __syncthreads();
    for (int b = tid; b < HIST_BINS; b += 256) h[b] = 0;  // zero for next pass
}

// Gather exactly min(C,2048) keys with (key>>shift) <= prefix.
__global__ void k_gather(const float* __restrict__ scores, char* wsb) {
    int img = blockIdx.x / BPI, blk = blockIdx.x % BPI;
    u32 sh = ((const u32*)(wsb + OFF_STATE + ST_SHIFT))[img];
    u64 P  = ((const u64*)(wsb + OFF_STATE + ST_PREFIX))[img];
    u32* gcnt = (u32*)(wsb + OFF_STATE + ST_GCNT);
    u64* selk = (u64*)(wsb + OFF_SELK) + (size_t)img * MPRE;
    const float* S = scores + (size_t)img * RR * SROW;
    for (int t = 0; t < 8; ++t) {
        int e = blk * 2048 + t * 256 + (int)threadIdx.x;
        if (e < NELEM) {
            int r = e / KK, c = e - r * KK;
            float s = S[(size_t)r * SROW + c];
            if (s > 0.05f) {
                u64 key = ((u64)(~__float_as_uint(s)) << 32) | (u32)e;
                if ((key >> sh) <= P) {
                    u32 pos = atomicAdd(&gcnt[img], 1u);
                    if (pos < MPRE) selk[pos] = key;
                }
            }
        }
    }
}

// Bitonic sort 2048 keys in LDS, decode candidates (clip, class-offset, area).
__global__ __launch_bounds__(1024) void k_sortdec(const float* __restrict__ boxes, char* wsb) {
    int img = blockIdx.x; int tid = threadIdx.x;
    __shared__ u64 sk[MPRE];
    u32 scnt = ((const u32*)(wsb + OFF_STATE + ST_GCNT))[img];
    if (scnt > MPRE) scnt = MPRE;
    const u64* selk = (const u64*)(wsb + OFF_SELK) + (size_t)img * MPRE;
    for (int i = tid; i < MPRE; i += 1024) sk[i] = (i < (int)scnt) ? selk[i] : ~0ull;
    for (u32 k2 = 2; k2 <= MPRE; k2 <<= 1) {
        for (u32 j = k2 >> 1; j > 0; j >>= 1) {
            __syncthreads();
            for (int i = tid; i < MPRE; i += 1024) {
                int ixj = i ^ (int)j;
                if (ixj > i) {
                    u64 a = sk[i], b = sk[ixj];
                    bool up = ((i & (int)k2) == 0);
                    if ((a > b) == up) { sk[i] = b; sk[ixj] = a; }
                }
            }
        }
    }
    __syncthreads();
    float4* cb   = (float4*)(wsb + OFF_CB)   + (size_t)img * MPRE;
    float4* ob   = (float4*)(wsb + OFF_OB)   + (size_t)img * MPRE;
    float*  area = (float*)(wsb + OFF_AREA)  + (size_t)img * MPRE;
    float*  scv  = (float*)(wsb + OFF_SCORE) + (size_t)img * MPRE;
    u32*    flv  = (u32*)(wsb + OFF_FLAT)    + (size_t)img * MPRE;
    for (int i = tid; i < MPRE; i += 1024) {
        if (i < (int)scnt) {
            u64 key = sk[i];
            u32 e = (u32)key;
            u32 sbits = ~((u32)(key >> 32));
            float sc = __uint_as_float(sbits);
            u32 r = e / KK, c = e - r * KK;
            const float* bp = boxes + (((size_t)img * RR + r) * KK + c) * 4;
            float x1 = fminf(fmaxf(bp[0], 0.0f), 1333.0f);
            float y1 = fminf(fmaxf(bp[1], 0.0f), 800.0f);
            float x2 = fminf(fmaxf(bp[2], 0.0f), 1333.0f);
            float y2 = fminf(fmaxf(bp[3], 0.0f), 800.0f);
            float coff = (float)c * 4096.0f;
            float ox1 = __fadd_rn(x1, coff), oy1 = __fadd_rn(y1, coff);
            float ox2 = __fadd_rn(x2, coff), oy2 = __fadd_rn(y2, coff);
            float ar = __fmul_rn(fmaxf(__fsub_rn(ox2, ox1), 0.0f),
                                 fmaxf(__fsub_rn(oy2, oy1), 0.0f));
            cb[i] = make_float4(x1, y1, x2, y2);
            ob[i] = make_float4(ox1, oy1, ox2, oy2);
            area[i] = ar; scv[i] = sc; flv[i] = e;
        } else {
            cb[i] = make_float4(0.f, 0.f, 0.f, 0.f);
            ob[i] = make_float4(0.f, 0.f, 0.f, 0.f);
            area[i] = 0.f; scv[i] = 0.f; flv[i] = 0u;
        }
    }
    if (tid == 0) ((u32*)(wsb + OFF_STATE + ST_CSEL))[img] = scnt;
}

// One wave per row: IoU vs all 2048 columns -> 32 u64 ballot words, j>i baked in.
__global__ void k_iou(char* wsb) {
    int gid = blockIdx.x; int img = gid >> 11; int i = gid & (MPRE - 1);
    int lane = threadIdx.x;
    const float4* ob   = (const float4*)(wsb + OFF_OB)  + (size_t)img * MPRE;
    const float*  area = (const float*)(wsb + OFF_AREA) + (size_t)img * MPRE;
    float4 bi = ob[i]; float ai = area[i];
    u64* row = (u64*)(wsb + OFF_SUP) + ((size_t)img * MPRE + i) * 32;
    for (int ch = 0; ch < 32; ++ch) {
        int j = ch * 64 + lane;
        float4 bj = ob[j]; float aj = area[j];
        float ltx = fmaxf(bi.x, bj.x), lty = fmaxf(bi.y, bj.y);
        float rbx = fminf(bi.z, bj.z), rby = fminf(bi.w, bj.w);
        float w = fmaxf(__fsub_rn(rbx, ltx), 0.0f);
        float h = fmaxf(__fsub_rn(rby, lty), 0.0f);
        float inter = __fmul_rn(w, h);
        float den = __fadd_rn(__fsub_rn(__fadd_rn(ai, aj), inter), 1e-9f);
        float iou = inter / den;
        bool pred = (iou > 0.5f) && (j > i);
        u64 m = __ballot(pred);
        if (lane == 0) row[ch] = m;
    }
}

// Greedy sequential NMS: one wave/image, lanes 0..31 own suppression words.
// Depth-16 unconditional row prefetch hides L2 latency of the serial chain.
__global__ void k_nms(char* wsb) {
    int img = blockIdx.x; int lane = threadIdx.x;
    int csel = (int)((const u32*)(wsb + OFF_STATE + ST_CSEL))[img];
    const u64* S = (const u64*)(wsb + OFF_SUP) + (size_t)img * MPRE * 32;
    u64 supw = 0;
    const int D = 16;
    u64 pre[D];
#pragma unroll
    for (int d = 0; d < D; ++d)
        pre[d] = (lane < 32 && d < csel) ? S[(size_t)d * 32 + lane] : 0ull;
    for (int base = 0; base < csel; base += D) {
#pragma unroll
        for (int d = 0; d < D; ++d) {
            int i = base + d;
            u64 row = pre[d];
            int ip = i + D;
            pre[d] = (lane < 32 && ip < csel) ? S[(size_t)ip * 32 + lane] : 0ull;
            if (i < csel) {
                u64 w = __shfl(supw, i >> 6);
                if (!((w >> (i & 63)) & 1ull)) {
                    if (lane < 32) supw |= row;
                }
            }
        }
    }
    if (lane < 32) {
        int b = lane << 6; u64 vw;
        if (csel >= b + 64) vw = ~0ull;
        else if (csel <= b) vw = 0ull;
        else vw = (1ull << (csel - b)) - 1ull;
        ((u64*)(wsb + OFF_KEEP))[img * 32 + lane] = vw & ~supw;
    }
}

// Rank kept candidates, gather rows [cb(4), score, logits(80)], zero the rest.
__global__ void k_out(const float* __restrict__ logits, char* wsb, float* __restrict__ out) {
    int img = blockIdx.x; int tid = threadIdx.x;
    __shared__ u64 kw[32];
    __shared__ u32 kpre[33];
    __shared__ int sel[NTOP];
    __shared__ int snk;
    if (tid < 32) kw[tid] = ((const u64*)(wsb + OFF_KEEP))[img * 32 + tid];
    __syncthreads();
    if (tid == 0) {
        u32 cum = 0;
        for (int w = 0; w < 32; ++w) { kpre[w] = cum; cum += (u32)__popcll(kw[w]); }
        kpre[32] = cum;
        snk = (cum < NTOP) ? (int)cum : NTOP;
    }
    __syncthreads();
    for (int i = tid; i < MPRE; i += 256) {
        u64 w = kw[i >> 6];
        if ((w >> (i & 63)) & 1ull) {
            u32 rank = kpre[i >> 6] + (u32)__popcll(w & ((1ull << (i & 63)) - 1ull));
            if (rank < NTOP) sel[rank] = i;
        }
    }
    __syncthreads();
    int nk = snk;
    const float4* cb  = (const float4*)(wsb + OFF_CB)   + (size_t)img * MPRE;
    const float*  scv = (const float*)(wsb + OFF_SCORE) + (size_t)img * MPRE;
    const u32*    flv = (const u32*)(wsb + OFF_FLAT)    + (size_t)img * MPRE;
    for (int idx = tid; idx < NTOP * 85; idx += 256) {
        int row = idx / 85, col = idx - row * 85;
        float v = 0.0f;
        if (row < nk) {
            int i = sel[row];
            if (col < 4) {
                float4 b = cb[i];
                v = (col == 0) ? b.x : (col == 1) ? b.y : (col == 2) ? b.z : b.w;
            } else if (col == 4) {
                v = scv[i];
            } else {
                u32 e = flv[i]; u32 r = e / KK;
                v = logits[((size_t)img * RR + r) * SROW + (u32)(col - 5)];
            }
        }
        out[(size_t)img * (NTOP * 85) + idx] = v;
    }
}

extern "C" void kernel_launch(void* const* d_in, const int* in_sizes, int n_in,
                              void* d_out, int out_size, void* d_ws, size_t ws_size,
                              hipStream_t stream) {
    const float* boxes  = (const float*)d_in[0];
    const float* scores = (const float*)d_in[1];
    const float* logits = (const float*)d_in[2];
    float* out = (float*)d_out;
    char* wsb = (char*)d_ws;

    int init_blocks = (int)((OFF_SELK / 4 + 255) / 256);
    k_init<<<init_blocks, 256, 0, stream>>>((u32*)d_ws);
    for (int p = 0; p < 4; ++p) {
        k_hist<<<NIMG * BPI, 256, 0, stream>>>(p, scores, wsb);
        k_pick<<<NIMG, 256, 0, stream>>>(p, wsb);
    }
    k_gather<<<NIMG * BPI, 256, 0, stream>>>(scores, wsb);
    k_sortdec<<<NIMG, 1024, 0, stream>>>(boxes, wsb);
    k_iou<<<NIMG * MPRE, 64, 0, stream>>>(wsb);
    k_nms<<<NIMG, 64, 0, stream>>>(wsb);
    k_out<<<NIMG, 256, 0, stream>>>(logits, wsb, out);
}

// Round 4
// 600.328 us; speedup vs baseline: 1.3769x; 1.3769x over previous
//
#include <hip/hip_runtime.h>

typedef unsigned int u32;
typedef unsigned long long u64;

#define NIMG 8
#define RR 10000
#define KK 80
#define SROW 81            // scores/logits row stride (K+1)
#define MPRE 2048
#define NTOP 100
#define NELEM (RR*KK)      // 800000 per image
#define BPI 391            // blocks/image for scan kernels: 391*2048 >= 800000
#define HIST_BINS 65536

// ---- workspace layout (bytes) ---- (identical to the proven round-1 layout, 7,145,728 B)
#define OFF_HIST   0ull
#define OFF_STATE  (8ull*HIST_BINS*4ull)              // 2,097,152
#define ST_DONE    0
#define ST_SHIFT   32
#define ST_NEED    64
#define ST_C       96
#define ST_GCNT    128
#define ST_CSEL    160
#define ST_PREFIX  192                                 // u64[8]
#define OFF_SELK   (OFF_STATE + 256)
#define OFF_CB     (OFF_SELK + 8ull*MPRE*8)
#define OFF_OB     (OFF_CB   + 8ull*MPRE*16)
#define OFF_AREA   (OFF_OB   + 8ull*MPRE*16)
#define OFF_SCORE  (OFF_AREA + 8ull*MPRE*4)
#define OFF_FLAT   (OFF_SCORE+ 8ull*MPRE*4)
#define OFF_SUP    (OFF_FLAT + 8ull*MPRE*4)
#define OFF_KEEP   (OFF_SUP  + 8ull*MPRE*32*8)
// total = OFF_KEEP + 2048 = 7,145,728 bytes — fits the ws round 1 ran in.

// Zero hist + per-image state; need[] initialized to MPRE by the covering thread.
__global__ void k_init(u32* ws32) {
    u32 idx = blockIdx.x * 256u + threadIdx.x;
    u32 nwords = (u32)(OFF_SELK / 4);
    if (idx < nwords) {
        u32 v = 0;
        u32 needbase = (u32)((OFF_STATE + ST_NEED) / 4);
        if (idx >= needbase && idx < needbase + 8) v = MPRE;
        ws32[idx] = v;
    }
}

// 16-bit radix histogram pass p (p=0..3). key = (~score_bits<<32)|flat_idx.
__global__ void k_hist(int p, const float* __restrict__ scores, char* wsb) {
    int img = blockIdx.x / BPI, blk = blockIdx.x % BPI;
    const u32* done = (const u32*)(wsb + OFF_STATE + ST_DONE);
    if (done[img]) return;
    u32 sh = 0; u64 P = 0;
    if (p > 0) {
        sh = ((const u32*)(wsb + OFF_STATE + ST_SHIFT))[img];
        P  = ((const u64*)(wsb + OFF_STATE + ST_PREFIX))[img];
    }
    u32* hist = (u32*)(wsb + OFF_HIST) + (size_t)img * HIST_BINS;
    const float* S = scores + (size_t)img * RR * SROW;
    int binshift = 48 - 16 * p;
    for (int t = 0; t < 8; ++t) {
        int e = blk * 2048 + t * 256 + (int)threadIdx.x;
        if (e < NELEM) {
            int r = e / KK, c = e - r * KK;
            float s = S[(size_t)r * SROW + c];
            if (s > 0.05f) {
                u64 key = ((u64)(~__float_as_uint(s)) << 32) | (u32)e;
                bool m = (p == 0) || ((key >> sh) == P);
                if (m) atomicAdd(&hist[(u32)((key >> binshift) & 0xFFFFull)], 1u);
            }
        }
    }
}

// Per-image bin selection. Fully parallel: two 256-wide scans, no serial search.
__global__ void k_pick(int p, char* wsb) {
    int img = blockIdx.x; int tid = threadIdx.x;
    u32* done = (u32*)(wsb + OFF_STATE + ST_DONE);
    __shared__ u32 sdone;
    __shared__ u32 sv[256];      // scan buffer
    __shared__ u32 sC[256];      // saved per-thread values
    __shared__ u32 sSel[2];      // {ck, cum_before_ck}
    __shared__ int sFin;
    if (tid == 0) sdone = done[img];
    __syncthreads();
    if (sdone) return;
    u32* h = (u32*)(wsb + OFF_HIST) + (size_t)img * HIST_BINS;
    // phase 1: per-thread sum over its 256-bin chunk, then inclusive scan
    u32 cs = 0; int b0 = tid * 256;
    for (int b = 0; b < 256; ++b) cs += h[b0 + b];
    sC[tid] = cs; sv[tid] = cs;
    __syncthreads();
    for (int off = 1; off < 256; off <<= 1) {
        u32 add = (tid >= off) ? sv[tid - off] : 0;
        __syncthreads();
        sv[tid] += add;
        __syncthreads();
    }
    u32 incl = sv[tid];
    u32 excl = incl - sC[tid];
    u32 total = sv[255];
    u32 need = ((const u32*)(wsb + OFF_STATE + ST_NEED))[img];
    if (tid == 0) {
        sFin = 0;
        if (p == 0) {
            ((u32*)(wsb + OFF_STATE + ST_C))[img] = total;
            if (total <= MPRE) {   // fewer than 2048 candidates: take all
                done[img] = 1;
                ((u32*)(wsb + OFF_STATE + ST_SHIFT))[img] = 0;
                ((u64*)(wsb + OFF_STATE + ST_PREFIX))[img] = ~0ull;
                sFin = 1;
            }
        }
    }
    __syncthreads();
    if (!sFin) {
        if (excl < need && incl >= need) { sSel[0] = (u32)tid; sSel[1] = excl; }
        __syncthreads();
        int ck = (int)sSel[0]; u32 cum = sSel[1];
        // phase 2: scan the 256 bins of the chosen chunk (1 parallel load each)
        u32 hb = h[ck * 256 + tid];
        sC[tid] = hb; sv[tid] = hb;
        __syncthreads();
        for (int off = 1; off < 256; off <<= 1) {
            u32 add = (tid >= off) ? sv[tid - off] : 0;
            __syncthreads();
            sv[tid] += add;
            __syncthreads();
        }
        u32 need2 = need - cum;
        u32 incl2 = sv[tid];
        u32 excl2 = incl2 - sC[tid];
        if (excl2 < need2 && incl2 >= need2) {   // this thread owns the boundary bin
            int bsel = ck * 256 + tid;
            u32 cntb = sC[tid];
            u32 rem  = need2 - excl2;            // rank within chosen bin, 1..cntb
            u64* prefA = (u64*)(wsb + OFF_STATE + ST_PREFIX);
            u64 P = (prefA[img] << 16) | (u32)bsel;
            prefA[img] = P;
            ((u32*)(wsb + OFF_STATE + ST_SHIFT))[img] = (u32)(48 - 16 * p);
            ((u32*)(wsb + OFF_STATE + ST_NEED))[img] = rem;
            if (rem == cntb || p == 3) done[img] = 1;  // whole bin taken => exact
        }
        __syncthreads();
    }
    for (int b = tid; b < HIST_BINS; b += 256) h[b] = 0;  // zero for next pass
}

// Gather exactly min(C,2048) keys with (key>>shift) <= prefix.
__global__ void k_gather(const float* __restrict__ scores, char* wsb) {
    int img = blockIdx.x / BPI, blk = blockIdx.x % BPI;
    u32 sh = ((const u32*)(wsb + OFF_STATE + ST_SHIFT))[img];
    u64 P  = ((const u64*)(wsb + OFF_STATE + ST_PREFIX))[img];
    u32* gcnt = (u32*)(wsb + OFF_STATE + ST_GCNT);
    u64* selk = (u64*)(wsb + OFF_SELK) + (size_t)img * MPRE;
    const float* S = scores + (size_t)img * RR * SROW;
    for (int t = 0; t < 8; ++t) {
        int e = blk * 2048 + t * 256 + (int)threadIdx.x;
        if (e < NELEM) {
            int r = e / KK, c = e - r * KK;
            float s = S[(size_t)r * SROW + c];
            if (s > 0.05f) {
                u64 key = ((u64)(~__float_as_uint(s)) << 32) | (u32)e;
                if ((key >> sh) <= P) {
                    u32 pos = atomicAdd(&gcnt[img], 1u);
                    if (pos < MPRE) selk[pos] = key;
                }
            }
        }
    }
}

// Bitonic sort 2048 keys in LDS, decode candidates (clip, class-offset, area).
__global__ __launch_bounds__(1024) void k_sortdec(const float* __restrict__ boxes, char* wsb) {
    int img = blockIdx.x; int tid = threadIdx.x;
    __shared__ u64 sk[MPRE];
    u32 scnt = ((const u32*)(wsb + OFF_STATE + ST_GCNT))[img];
    if (scnt > MPRE) scnt = MPRE;
    const u64* selk = (const u64*)(wsb + OFF_SELK) + (size_t)img * MPRE;
    for (int i = tid; i < MPRE; i += 1024) sk[i] = (i < (int)scnt) ? selk[i] : ~0ull;
    for (u32 k2 = 2; k2 <= MPRE; k2 <<= 1) {
        for (u32 j = k2 >> 1; j > 0; j >>= 1) {
            __syncthreads();
            for (int i = tid; i < MPRE; i += 1024) {
                int ixj = i ^ (int)j;
                if (ixj > i) {
                    u64 a = sk[i], b = sk[ixj];
                    bool up = ((i & (int)k2) == 0);
                    if ((a > b) == up) { sk[i] = b; sk[ixj] = a; }
                }
            }
        }
    }
    __syncthreads();
    float4* cb   = (float4*)(wsb + OFF_CB)   + (size_t)img * MPRE;
    float4* ob   = (float4*)(wsb + OFF_OB)   + (size_t)img * MPRE;
    float*  area = (float*)(wsb + OFF_AREA)  + (size_t)img * MPRE;
    float*  scv  = (float*)(wsb + OFF_SCORE) + (size_t)img * MPRE;
    u32*    flv  = (u32*)(wsb + OFF_FLAT)    + (size_t)img * MPRE;
    for (int i = tid; i < MPRE; i += 1024) {
        if (i < (int)scnt) {
            u64 key = sk[i];
            u32 e = (u32)key;
            u32 sbits = ~((u32)(key >> 32));
            float sc = __uint_as_float(sbits);
            u32 r = e / KK, c = e - r * KK;
            const float* bp = boxes + (((size_t)img * RR + r) * KK + c) * 4;
            float x1 = fminf(fmaxf(bp[0], 0.0f), 1333.0f);
            float y1 = fminf(fmaxf(bp[1], 0.0f), 800.0f);
            float x2 = fminf(fmaxf(bp[2], 0.0f), 1333.0f);
            float y2 = fminf(fmaxf(bp[3], 0.0f), 800.0f);
            float coff = (float)c * 4096.0f;
            float ox1 = __fadd_rn(x1, coff), oy1 = __fadd_rn(y1, coff);
            float ox2 = __fadd_rn(x2, coff), oy2 = __fadd_rn(y2, coff);
            float ar = __fmul_rn(fmaxf(__fsub_rn(ox2, ox1), 0.0f),
                                 fmaxf(__fsub_rn(oy2, oy1), 0.0f));
            cb[i] = make_float4(x1, y1, x2, y2);
            ob[i] = make_float4(ox1, oy1, ox2, oy2);
            area[i] = ar; scv[i] = sc; flv[i] = e;
        } else {
            cb[i] = make_float4(0.f, 0.f, 0.f, 0.f);
            ob[i] = make_float4(0.f, 0.f, 0.f, 0.f);
            area[i] = 0.f; scv[i] = 0.f; flv[i] = 0u;
        }
    }
    if (tid == 0) ((u32*)(wsb + OFF_STATE + ST_CSEL))[img] = scnt;
}

// 8 rows per 512-thread block (one wave per row); box table staged once in LDS.
// IoU vs all 2048 columns -> 32 u64 ballot words, j>i baked in.
__global__ __launch_bounds__(512) void k_iou(char* wsb) {
    int blk = blockIdx.x;                 // 2048 blocks
    int img = blk >> 8; int row0 = (blk & 255) * 8;
    int tid = threadIdx.x;
    __shared__ float4 sob[MPRE];
    __shared__ float  sarea[MPRE];
    const float4* ob   = (const float4*)(wsb + OFF_OB)  + (size_t)img * MPRE;
    const float*  area = (const float*)(wsb + OFF_AREA) + (size_t)img * MPRE;
    for (int i = tid; i < MPRE; i += 512) { sob[i] = ob[i]; sarea[i] = area[i]; }
    __syncthreads();
    int wid = tid >> 6, lane = tid & 63;
    int i = row0 + wid;
    float4 bi = sob[i]; float ai = sarea[i];
    u64* row = (u64*)(wsb + OFF_SUP) + ((size_t)img * MPRE + i) * 32;
    for (int ch = 0; ch < 32; ++ch) {
        int j = ch * 64 + lane;
        float4 bj = sob[j]; float aj = sarea[j];
        float ltx = fmaxf(bi.x, bj.x), lty = fmaxf(bi.y, bj.y);
        float rbx = fminf(bi.z, bj.z), rby = fminf(bi.w, bj.w);
        float w = fmaxf(__fsub_rn(rbx, ltx), 0.0f);
        float h = fmaxf(__fsub_rn(rby, lty), 0.0f);
        float inter = __fmul_rn(w, h);
        float den = __fadd_rn(__fsub_rn(__fadd_rn(ai, aj), inter), 1e-9f);
        float iou = inter / den;
        bool pred = (iou > 0.5f) && (j > i);
        u64 m = __ballot(pred);
        if (lane == 0) row[ch] = m;
    }
}

// Greedy sequential NMS, one wave/image. Lanes 0..31 own suppression words.
// bcur = lane-uniform copy of the word being scanned (broadcast load keeps the
// per-iteration chain register-only); early exit once 100 boxes are kept:
// suppression flows strictly forward (j>i), so keep bits after the 100th keep
// can only produce ranks >= 100, which k_out ignores.
__global__ void k_nms(char* wsb) {
    int img = blockIdx.x; int lane = threadIdx.x;
    int csel = (int)((const u32*)(wsb + OFF_STATE + ST_CSEL))[img];
    const u64* S = (const u64*)(wsb + OFF_SUP) + (size_t)img * MPRE * 32;
    u64 supw = 0;      // lanes 0..31: suppression word #lane
    u64 bcur = 0;      // all lanes: current word (i>>6), kept lane-uniform
    int kcnt = 0;
    bool doneF = false;
    const int D = 16;
    u64 pre[D]; u64 preb[D];
#pragma unroll
    for (int d = 0; d < D; ++d) {
        pre[d]  = (lane < 32 && d < csel) ? S[(size_t)d * 32 + lane] : 0ull;
        preb[d] = (d < csel) ? S[(size_t)d * 32 + 0] : 0ull;  // word 0 for rows 0..15
    }
    for (int base = 0; base < csel && !doneF; base += D) {
        int w = base >> 6;
        if ((base & 63) == 0) bcur = __shfl(supw, w);  // word change: resync
        int wn = (base + D) >> 6;
#pragma unroll
        for (int d = 0; d < D; ++d) {
            int i = base + d;
            u64 rowl = pre[d]; u64 rowb = preb[d];
            int ip = i + D;
            pre[d]  = (lane < 32 && ip < csel) ? S[(size_t)ip * 32 + lane] : 0ull;
            preb[d] = (ip < csel) ? S[(size_t)ip * 32 + wn] : 0ull;
            if (i < csel && !doneF) {
                bool kept = !((bcur >> (i & 63)) & 1ull);
                if (kept) {
                    if (lane < 32) supw |= rowl;
                    bcur |= rowb;
                    if (++kcnt >= NTOP) doneF = true;
                }
            }
        }
    }
    if (lane < 32) {
        int b = lane << 6; u64 vw;
        if (csel >= b + 64) vw = ~0ull;
        else if (csel <= b) vw = 0ull;
        else vw = (1ull << (csel - b)) - 1ull;
        ((u64*)(wsb + OFF_KEEP))[img * 32 + lane] = vw & ~supw;
    }
}

// Rank kept candidates, gather rows [cb(4), score, logits(80)], zero the rest.
__global__ void k_out(const float* __restrict__ logits, char* wsb, float* __restrict__ out) {
    int img = blockIdx.x; int tid = threadIdx.x;
    __shared__ u64 kw[32];
    __shared__ u32 kpre[33];
    __shared__ int sel[NTOP];
    __shared__ int snk;
    if (tid < 32) kw[tid] = ((const u64*)(wsb + OFF_KEEP))[img * 32 + tid];
    __syncthreads();
    if (tid == 0) {
        u32 cum = 0;
        for (int w = 0; w < 32; ++w) { kpre[w] = cum; cum += (u32)__popcll(kw[w]); }
        kpre[32] = cum;
        snk = (cum < NTOP) ? (int)cum : NTOP;
    }
    __syncthreads();
    for (int i = tid; i < MPRE; i += 256) {
        u64 w = kw[i >> 6];
        if ((w >> (i & 63)) & 1ull) {
            u32 rank = kpre[i >> 6] + (u32)__popcll(w & ((1ull << (i & 63)) - 1ull));
            if (rank < NTOP) sel[rank] = i;
        }
    }
    __syncthreads();
    int nk = snk;
    const float4* cb  = (const float4*)(wsb + OFF_CB)   + (size_t)img * MPRE;
    const float*  scv = (const float*)(wsb + OFF_SCORE) + (size_t)img * MPRE;
    const u32*    flv = (const u32*)(wsb + OFF_FLAT)    + (size_t)img * MPRE;
    for (int idx = tid; idx < NTOP * 85; idx += 256) {
        int row = idx / 85, col = idx - row * 85;
        float v = 0.0f;
        if (row < nk) {
            int i = sel[row];
            if (col < 4) {
                float4 b = cb[i];
                v = (col == 0) ? b.x : (col == 1) ? b.y : (col == 2) ? b.z : b.w;
            } else if (col == 4) {
                v = scv[i];
            } else {
                u32 e = flv[i]; u32 r = e / KK;
                v = logits[((size_t)img * RR + r) * SROW + (u32)(col - 5)];
            }
        }
        out[(size_t)img * (NTOP * 85) + idx] = v;
    }
}

extern "C" void kernel_launch(void* const* d_in, const int* in_sizes, int n_in,
                              void* d_out, int out_size, void* d_ws, size_t ws_size,
                              hipStream_t stream) {
    const float* boxes  = (const float*)d_in[0];
    const float* scores = (const float*)d_in[1];
    const float* logits = (const float*)d_in[2];
    float* out = (float*)d_out;
    char* wsb = (char*)d_ws;

    int init_blocks = (int)((OFF_SELK / 4 + 255) / 256);
    k_init<<<init_blocks, 256, 0, stream>>>((u32*)d_ws);
    for (int p = 0; p < 4; ++p) {
        k_hist<<<NIMG * BPI, 256, 0, stream>>>(p, scores, wsb);
        k_pick<<<NIMG, 256, 0, stream>>>(p, wsb);
    }
    k_gather<<<NIMG * BPI, 256, 0, stream>>>(scores, wsb);
    k_sortdec<<<NIMG, 1024, 0, stream>>>(boxes, wsb);
    k_iou<<<NIMG * 256, 512, 0, stream>>>(wsb);
    k_nms<<<NIMG, 64, 0, stream>>>(wsb);
    k_out<<<NIMG, 256, 0, stream>>>(logits, wsb, out);
}

// Round 5
// 433.059 us; speedup vs baseline: 1.9087x; 1.3863x over previous
//
#include <hip/hip_runtime.h>

typedef unsigned int u32;
typedef unsigned long long u64;

#define NIMG 8
#define RR 10000
#define KK 80
#define SROW 81            // scores/logits row stride (K+1)
#define MPRE 2048
#define NTOP 100
#define NELEM (RR*KK)      // 800000 per image
#define BPI 391            // blocks/image for scan kernels: 391*2048 >= 800000
#define HIST_BINS 65536

// ---- workspace layout (bytes) ---- (identical to the proven round-1 layout, 7,145,728 B)
#define OFF_HIST   0ull
#define OFF_STATE  (8ull*HIST_BINS*4ull)              // 2,097,152
#define ST_DONE    0
#define ST_SHIFT   32
#define ST_NEED    64
#define ST_C       96
#define ST_GCNT    128
#define ST_CSEL    160
#define ST_PREFIX  192                                 // u64[8]
#define OFF_SELK   (OFF_STATE + 256)
#define OFF_CB     (OFF_SELK + 8ull*MPRE*8)
#define OFF_OB     (OFF_CB   + 8ull*MPRE*16)
#define OFF_AREA   (OFF_OB   + 8ull*MPRE*16)
#define OFF_SCORE  (OFF_AREA + 8ull*MPRE*4)
#define OFF_FLAT   (OFF_SCORE+ 8ull*MPRE*4)
#define OFF_SUP    (OFF_FLAT + 8ull*MPRE*4)
#define OFF_KEEP   (OFF_SUP  + 8ull*MPRE*32*8)
// total = OFF_KEEP + 2048 = 7,145,728 bytes — fits the ws round 1 ran in.

// Gather counters: reuse hist[img*HIST_BINS] (zeroed by k_pick's final pass,
// 256 KB apart -> no false sharing). ST_GCNT retained but unused.
#define GCNT_PTR(wsb, img) ((u32*)((wsb) + OFF_HIST) + (size_t)(img) * HIST_BINS)

// Zero hist + per-image state; need[] initialized to MPRE by the covering thread.
__global__ void k_init(u32* ws32) {
    u32 idx = blockIdx.x * 256u + threadIdx.x;
    u32 nwords = (u32)(OFF_SELK / 4);
    if (idx < nwords) {
        u32 v = 0;
        u32 needbase = (u32)((OFF_STATE + ST_NEED) / 4);
        if (idx >= needbase && idx < needbase + 8) v = MPRE;
        ws32[idx] = v;
    }
}

// 16-bit radix histogram pass p (p=0..3). key = (~score_bits<<32)|flat_idx.
__global__ void k_hist(int p, const float* __restrict__ scores, char* wsb) {
    int img = blockIdx.x / BPI, blk = blockIdx.x % BPI;
    const u32* done = (const u32*)(wsb + OFF_STATE + ST_DONE);
    if (done[img]) return;
    u32 sh = 0; u64 P = 0;
    if (p > 0) {
        sh = ((const u32*)(wsb + OFF_STATE + ST_SHIFT))[img];
        P  = ((const u64*)(wsb + OFF_STATE + ST_PREFIX))[img];
    }
    u32* hist = (u32*)(wsb + OFF_HIST) + (size_t)img * HIST_BINS;
    const float* S = scores + (size_t)img * RR * SROW;
    int binshift = 48 - 16 * p;
    for (int t = 0; t < 8; ++t) {
        int e = blk * 2048 + t * 256 + (int)threadIdx.x;
        if (e < NELEM) {
            int r = e / KK, c = e - r * KK;
            float s = S[(size_t)r * SROW + c];
            if (s > 0.05f) {
                u64 key = ((u64)(~__float_as_uint(s)) << 32) | (u32)e;
                bool m = (p == 0) || ((key >> sh) == P);
                if (m) atomicAdd(&hist[(u32)((key >> binshift) & 0xFFFFull)], 1u);
            }
        }
    }
}

// Per-image bin selection. Fully parallel: two 256-wide scans, no serial search.
__global__ void k_pick(int p, char* wsb) {
    int img = blockIdx.x; int tid = threadIdx.x;
    u32* done = (u32*)(wsb + OFF_STATE + ST_DONE);
    __shared__ u32 sdone;
    __shared__ u32 sv[256];      // scan buffer
    __shared__ u32 sC[256];      // saved per-thread values
    __shared__ u32 sSel[2];      // {ck, cum_before_ck}
    __shared__ int sFin;
    if (tid == 0) sdone = done[img];
    __syncthreads();
    if (sdone) return;
    u32* h = (u32*)(wsb + OFF_HIST) + (size_t)img * HIST_BINS;
    // phase 1: per-thread sum over its 256-bin chunk, then inclusive scan
    u32 cs = 0; int b0 = tid * 256;
    for (int b = 0; b < 256; ++b) cs += h[b0 + b];
    sC[tid] = cs; sv[tid] = cs;
    __syncthreads();
    for (int off = 1; off < 256; off <<= 1) {
        u32 add = (tid >= off) ? sv[tid - off] : 0;
        __syncthreads();
        sv[tid] += add;
        __syncthreads();
    }
    u32 incl = sv[tid];
    u32 excl = incl - sC[tid];
    u32 total = sv[255];
    u32 need = ((const u32*)(wsb + OFF_STATE + ST_NEED))[img];
    if (tid == 0) {
        sFin = 0;
        if (p == 0) {
            ((u32*)(wsb + OFF_STATE + ST_C))[img] = total;
            if (total <= MPRE) {   // fewer than 2048 candidates: take all
                done[img] = 1;
                ((u32*)(wsb + OFF_STATE + ST_SHIFT))[img] = 0;
                ((u64*)(wsb + OFF_STATE + ST_PREFIX))[img] = ~0ull;
                sFin = 1;
            }
        }
    }
    __syncthreads();
    if (!sFin) {
        if (excl < need && incl >= need) { sSel[0] = (u32)tid; sSel[1] = excl; }
        __syncthreads();
        int ck = (int)sSel[0]; u32 cum = sSel[1];
        // phase 2: scan the 256 bins of the chosen chunk (1 parallel load each)
        u32 hb = h[ck * 256 + tid];
        sC[tid] = hb; sv[tid] = hb;
        __syncthreads();
        for (int off = 1; off < 256; off <<= 1) {
            u32 add = (tid >= off) ? sv[tid - off] : 0;
            __syncthreads();
            sv[tid] += add;
            __syncthreads();
        }
        u32 need2 = need - cum;
        u32 incl2 = sv[tid];
        u32 excl2 = incl2 - sC[tid];
        if (excl2 < need2 && incl2 >= need2) {   // this thread owns the boundary bin
            int bsel = ck * 256 + tid;
            u32 cntb = sC[tid];
            u32 rem  = need2 - excl2;            // rank within chosen bin, 1..cntb
            u64* prefA = (u64*)(wsb + OFF_STATE + ST_PREFIX);
            u64 P = (prefA[img] << 16) | (u32)bsel;
            prefA[img] = P;
            ((u32*)(wsb + OFF_STATE + ST_SHIFT))[img] = (u32)(48 - 16 * p);
            ((u32*)(wsb + OFF_STATE + ST_NEED))[img] = rem;
            if (rem == cntb || p == 3) done[img] = 1;  // whole bin taken => exact
        }
        __syncthreads();
    }
    for (int b = tid; b < HIST_BINS; b += 256) h[b] = 0;  // zero for next pass
}

// Gather exactly min(C,2048) keys with (key>>shift) <= prefix.
// Two-phase per block: LDS-buffer candidates (block-local atomic), then ONE
// global atomicAdd per block to reserve a range (391 atomics/image instead of
// ~2048 same-line RMWs -> kills the 185us cross-XCD atomic serialization).
__global__ void k_gather(const float* __restrict__ scores, char* wsb) {
    int img = blockIdx.x / BPI, blk = blockIdx.x % BPI;
    u32 sh = ((const u32*)(wsb + OFF_STATE + ST_SHIFT))[img];
    u64 P  = ((const u64*)(wsb + OFF_STATE + ST_PREFIX))[img];
    __shared__ u64 lbuf[2048];   // worst case: every element of the block passes
    __shared__ u32 lcnt;
    __shared__ u32 lbase;
    if (threadIdx.x == 0) lcnt = 0;
    __syncthreads();
    const float* S = scores + (size_t)img * RR * SROW;
    for (int t = 0; t < 8; ++t) {
        int e = blk * 2048 + t * 256 + (int)threadIdx.x;
        if (e < NELEM) {
            int r = e / KK, c = e - r * KK;
            float s = S[(size_t)r * SROW + c];
            if (s > 0.05f) {
                u64 key = ((u64)(~__float_as_uint(s)) << 32) | (u32)e;
                if ((key >> sh) <= P) {
                    u32 p = atomicAdd(&lcnt, 1u);
                    lbuf[p] = key;
                }
            }
        }
    }
    __syncthreads();
    if (threadIdx.x == 0) {
        lbase = (lcnt > 0) ? atomicAdd(GCNT_PTR(wsb, img), lcnt) : 0u;
    }
    __syncthreads();
    u32 n = lcnt, base = lbase;
    u64* selk = (u64*)(wsb + OFF_SELK) + (size_t)img * MPRE;
    for (u32 i = threadIdx.x; i < n; i += 256) {
        u32 pos = base + i;
        if (pos < MPRE) selk[pos] = lbuf[i];
    }
}

// Bitonic sort 2048 keys in LDS, decode candidates (clip, class-offset, area).
__global__ __launch_bounds__(1024) void k_sortdec(const float* __restrict__ boxes, char* wsb) {
    int img = blockIdx.x; int tid = threadIdx.x;
    __shared__ u64 sk[MPRE];
    u32 scnt = *GCNT_PTR(wsb, img);          // gather counter (relocated)
    if (scnt > MPRE) scnt = MPRE;
    const u64* selk = (const u64*)(wsb + OFF_SELK) + (size_t)img * MPRE;
    for (int i = tid; i < MPRE; i += 1024) sk[i] = (i < (int)scnt) ? selk[i] : ~0ull;
    for (u32 k2 = 2; k2 <= MPRE; k2 <<= 1) {
        for (u32 j = k2 >> 1; j > 0; j >>= 1) {
            __syncthreads();
            for (int i = tid; i < MPRE; i += 1024) {
                int ixj = i ^ (int)j;
                if (ixj > i) {
                    u64 a = sk[i], b = sk[ixj];
                    bool up = ((i & (int)k2) == 0);
                    if ((a > b) == up) { sk[i] = b; sk[ixj] = a; }
                }
            }
        }
    }
    __syncthreads();
    float4* cb   = (float4*)(wsb + OFF_CB)   + (size_t)img * MPRE;
    float4* ob   = (float4*)(wsb + OFF_OB)   + (size_t)img * MPRE;
    float*  area = (float*)(wsb + OFF_AREA)  + (size_t)img * MPRE;
    float*  scv  = (float*)(wsb + OFF_SCORE) + (size_t)img * MPRE;
    u32*    flv  = (u32*)(wsb + OFF_FLAT)    + (size_t)img * MPRE;
    for (int i = tid; i < MPRE; i += 1024) {
        if (i < (int)scnt) {
            u64 key = sk[i];
            u32 e = (u32)key;
            u32 sbits = ~((u32)(key >> 32));
            float sc = __uint_as_float(sbits);
            u32 r = e / KK, c = e - r * KK;
            const float* bp = boxes + (((size_t)img * RR + r) * KK + c) * 4;
            float x1 = fminf(fmaxf(bp[0], 0.0f), 1333.0f);
            float y1 = fminf(fmaxf(bp[1], 0.0f), 800.0f);
            float x2 = fminf(fmaxf(bp[2], 0.0f), 1333.0f);
            float y2 = fminf(fmaxf(bp[3], 0.0f), 800.0f);
            float coff = (float)c * 4096.0f;
            float ox1 = __fadd_rn(x1, coff), oy1 = __fadd_rn(y1, coff);
            float ox2 = __fadd_rn(x2, coff), oy2 = __fadd_rn(y2, coff);
            float ar = __fmul_rn(fmaxf(__fsub_rn(ox2, ox1), 0.0f),
                                 fmaxf(__fsub_rn(oy2, oy1), 0.0f));
            cb[i] = make_float4(x1, y1, x2, y2);
            ob[i] = make_float4(ox1, oy1, ox2, oy2);
            area[i] = ar; scv[i] = sc; flv[i] = e;
        } else {
            cb[i] = make_float4(0.f, 0.f, 0.f, 0.f);
            ob[i] = make_float4(0.f, 0.f, 0.f, 0.f);
            area[i] = 0.f; scv[i] = 0.f; flv[i] = 0u;
        }
    }
    if (tid == 0) ((u32*)(wsb + OFF_STATE + ST_CSEL))[img] = scnt;
}

// 8 rows per 512-thread block (one wave per row); box table staged once in LDS.
// IoU vs all 2048 columns -> 32 u64 ballot words, j>i baked in.
__global__ __launch_bounds__(512) void k_iou(char* wsb) {
    int blk = blockIdx.x;                 // 2048 blocks
    int img = blk >> 8; int row0 = (blk & 255) * 8;
    int tid = threadIdx.x;
    __shared__ float4 sob[MPRE];
    __shared__ float  sarea[MPRE];
    const float4* ob   = (const float4*)(wsb + OFF_OB)  + (size_t)img * MPRE;
    const float*  area = (const float*)(wsb + OFF_AREA) + (size_t)img * MPRE;
    for (int i = tid; i < MPRE; i += 512) { sob[i] = ob[i]; sarea[i] = area[i]; }
    __syncthreads();
    int wid = tid >> 6, lane = tid & 63;
    int i = row0 + wid;
    float4 bi = sob[i]; float ai = sarea[i];
    u64* row = (u64*)(wsb + OFF_SUP) + ((size_t)img * MPRE + i) * 32;
    for (int ch = 0; ch < 32; ++ch) {
        int j = ch * 64 + lane;
        float4 bj = sob[j]; float aj = sarea[j];
        float ltx = fmaxf(bi.x, bj.x), lty = fmaxf(bi.y, bj.y);
        float rbx = fminf(bi.z, bj.z), rby = fminf(bi.w, bj.w);
        float w = fmaxf(__fsub_rn(rbx, ltx), 0.0f);
        float h = fmaxf(__fsub_rn(rby, lty), 0.0f);
        float inter = __fmul_rn(w, h);
        float den = __fadd_rn(__fsub_rn(__fadd_rn(ai, aj), inter), 1e-9f);
        float iou = inter / den;
        bool pred = (iou > 0.5f) && (j > i);
        u64 m = __ballot(pred);
        if (lane == 0) row[ch] = m;
    }
}

// Greedy sequential NMS, one wave/image. Lanes 0..31 own suppression words.
// bcur = lane-uniform copy of the word being scanned (broadcast load keeps the
// per-iteration chain register-only); early exit once 100 boxes are kept:
// suppression flows strictly forward (j>i), so keep bits after the 100th keep
// can only produce ranks >= 100, which k_out ignores.
__global__ void k_nms(char* wsb) {
    int img = blockIdx.x; int lane = threadIdx.x;
    int csel = (int)((const u32*)(wsb + OFF_STATE + ST_CSEL))[img];
    const u64* S = (const u64*)(wsb + OFF_SUP) + (size_t)img * MPRE * 32;
    u64 supw = 0;      // lanes 0..31: suppression word #lane
    u64 bcur = 0;      // all lanes: current word (i>>6), kept lane-uniform
    int kcnt = 0;
    bool doneF = false;
    const int D = 16;
    u64 pre[D]; u64 preb[D];
#pragma unroll
    for (int d = 0; d < D; ++d) {
        pre[d]  = (lane < 32 && d < csel) ? S[(size_t)d * 32 + lane] : 0ull;
        preb[d] = (d < csel) ? S[(size_t)d * 32 + 0] : 0ull;  // word 0 for rows 0..15
    }
    for (int base = 0; base < csel && !doneF; base += D) {
        int w = base >> 6;
        if ((base & 63) == 0) bcur = __shfl(supw, w);  // word change: resync
        int wn = (base + D) >> 6;
#pragma unroll
        for (int d = 0; d < D; ++d) {
            int i = base + d;
            u64 rowl = pre[d]; u64 rowb = preb[d];
            int ip = i + D;
            pre[d]  = (lane < 32 && ip < csel) ? S[(size_t)ip * 32 + lane] : 0ull;
            preb[d] = (ip < csel) ? S[(size_t)ip * 32 + wn] : 0ull;
            if (i < csel && !doneF) {
                bool kept = !((bcur >> (i & 63)) & 1ull);
                if (kept) {
                    if (lane < 32) supw |= rowl;
                    bcur |= rowb;
                    if (++kcnt >= NTOP) doneF = true;
                }
            }
        }
    }
    if (lane < 32) {
        int b = lane << 6; u64 vw;
        if (csel >= b + 64) vw = ~0ull;
        else if (csel <= b) vw = 0ull;
        else vw = (1ull << (csel - b)) - 1ull;
        ((u64*)(wsb + OFF_KEEP))[img * 32 + lane] = vw & ~supw;
    }
}

// Rank kept candidates, gather rows [cb(4), score, logits(80)], zero the rest.
__global__ void k_out(const float* __restrict__ logits, char* wsb, float* __restrict__ out) {
    int img = blockIdx.x; int tid = threadIdx.x;
    __shared__ u64 kw[32];
    __shared__ u32 kpre[33];
    __shared__ int sel[NTOP];
    __shared__ int snk;
    if (tid < 32) kw[tid] = ((const u64*)(wsb + OFF_KEEP))[img * 32 + tid];
    __syncthreads();
    if (tid == 0) {
        u32 cum = 0;
        for (int w = 0; w < 32; ++w) { kpre[w] = cum; cum += (u32)__popcll(kw[w]); }
        kpre[32] = cum;
        snk = (cum < NTOP) ? (int)cum : NTOP;
    }
    __syncthreads();
    for (int i = tid; i < MPRE; i += 256) {
        u64 w = kw[i >> 6];
        if ((w >> (i & 63)) & 1ull) {
            u32 rank = kpre[i >> 6] + (u32)__popcll(w & ((1ull << (i & 63)) - 1ull));
            if (rank < NTOP) sel[rank] = i;
        }
    }
    __syncthreads();
    int nk = snk;
    const float4* cb  = (const float4*)(wsb + OFF_CB)   + (size_t)img * MPRE;
    const float*  scv = (const float*)(wsb + OFF_SCORE) + (size_t)img * MPRE;
    const u32*    flv = (const u32*)(wsb + OFF_FLAT)    + (size_t)img * MPRE;
    for (int idx = tid; idx < NTOP * 85; idx += 256) {
        int row = idx / 85, col = idx - row * 85;
        float v = 0.0f;
        if (row < nk) {
            int i = sel[row];
            if (col < 4) {
                float4 b = cb[i];
                v = (col == 0) ? b.x : (col == 1) ? b.y : (col == 2) ? b.z : b.w;
            } else if (col == 4) {
                v = scv[i];
            } else {
                u32 e = flv[i]; u32 r = e / KK;
                v = logits[((size_t)img * RR + r) * SROW + (u32)(col - 5)];
            }
        }
        out[(size_t)img * (NTOP * 85) + idx] = v;
    }
}

extern "C" void kernel_launch(void* const* d_in, const int* in_sizes, int n_in,
                              void* d_out, int out_size, void* d_ws, size_t ws_size,
                              hipStream_t stream) {
    const float* boxes  = (const float*)d_in[0];
    const float* scores = (const float*)d_in[1];
    const float* logits = (const float*)d_in[2];
    float* out = (float*)d_out;
    char* wsb = (char*)d_ws;

    int init_blocks = (int)((OFF_SELK / 4 + 255) / 256);
    k_init<<<init_blocks, 256, 0, stream>>>((u32*)d_ws);
    for (int p = 0; p < 4; ++p) {
        k_hist<<<NIMG * BPI, 256, 0, stream>>>(p, scores, wsb);
        k_pick<<<NIMG, 256, 0, stream>>>(p, wsb);
    }
    k_gather<<<NIMG * BPI, 256, 0, stream>>>(scores, wsb);
    k_sortdec<<<NIMG, 1024, 0, stream>>>(boxes, wsb);
    k_iou<<<NIMG * 256, 512, 0, stream>>>(wsb);
    k_nms<<<NIMG, 64, 0, stream>>>(wsb);
    k_out<<<NIMG, 256, 0, stream>>>(logits, wsb, out);
}

// Round 7
// 369.312 us; speedup vs baseline: 2.2381x; 1.1726x over previous
//
#include <hip/hip_runtime.h>

typedef unsigned int u32;
typedef unsigned long long u64;

#define NIMG 8
#define RR 10000
#define KK 80
#define SROW 81            // scores/logits row stride (K+1)
#define MPRE 2048
#define NTOP 100
#define NELEM (RR*KK)      // 800000 per image
#define BPI 391            // blocks/image for full-scan fallback: 391*2048 >= 800000
#define HIST_BINS 65536

#define P0B 64             // pass-0 blocks per image
#define P0E ((NELEM + P0B - 1) / P0B)   // 12500 elements per pass-0 block
#define CBINS 1024         // compressed pass-0 bins
#define CBASE 0xC07Fu      // min value of key>>48 for s in (0.05, 1.0]
#define BUFCAP 3328        // >= 158 rows * 20 cands max per pass-0 block
#define CAP2 65536         // compact-list capacity per image (fallback if exceeded)

// ---- workspace layout (bytes) ---- (identical size to the proven 7,145,728 B)
#define OFF_HIST   0ull
#define OFF_STATE  (8ull*HIST_BINS*4ull)              // 2,097,152
#define ST_DONE    0
#define ST_SHIFT   32
#define ST_NEED    64
#define ST_C       96
#define ST_CCNT    128      // FIXED: was 224, which overlapped ST_PREFIX[4..7]
#define ST_CSEL    160
#define ST_PREFIX  192      // u64[8] -> bytes 192..256
#define OFF_SELK   (OFF_STATE + 256)
#define OFF_CB     (OFF_SELK + 8ull*MPRE*8)
#define OFF_OB     (OFF_CB   + 8ull*MPRE*16)
#define OFF_AREA   (OFF_OB   + 8ull*MPRE*16)
#define OFF_SCORE  (OFF_AREA + 8ull*MPRE*4)
#define OFF_FLAT   (OFF_SCORE+ 8ull*MPRE*4)
#define OFF_SUP    (OFF_FLAT + 8ull*MPRE*4)
#define OFF_KEEP   (OFF_SUP  + 8ull*MPRE*32*8)
// Compact candidate list ALIASES the suppression matrix: cand is dead before
// k_iou writes sup (stream-ordered). 8*CAP2*8 = 4,194,304 = sizeof(SUP) exactly.
#define OFF_CAND   OFF_SUP

// Gather counter: hist bin 0 of each image (always zero by gather time).
#define GCNT_PTR(wsb, img) ((u32*)((wsb) + OFF_HIST) + (size_t)(img) * HIST_BINS)

// Zero hist + per-image state; need[] initialized to MPRE by the covering thread.
__global__ void k_init(u32* ws32) {
    u32 idx = blockIdx.x * 256u + threadIdx.x;
    u32 nwords = (u32)(OFF_SELK / 4);
    if (idx < nwords) {
        u32 v = 0;
        u32 needbase = (u32)((OFF_STATE + ST_NEED) / 4);
        if (idx >= needbase && idx < needbase + 8) v = MPRE;
        ws32[idx] = v;
    }
}

// Pass 0: one full scan. Per-block LDS hist over 1024 compressed bins ->
// private partial-hist slice (NO global atomics); compact candidate list via
// two-phase LDS buffer (one global atomicAdd per block).
__global__ __launch_bounds__(256) void k_hist0(const float* __restrict__ scores, char* wsb) {
    int img = blockIdx.x / P0B, blk = blockIdx.x % P0B;
    int tid = threadIdx.x;
    __shared__ u32 lh[CBINS];
    __shared__ u64 lbuf[BUFCAP];
    __shared__ u32 lcnt, lbase;
    for (int b = tid; b < CBINS; b += 256) lh[b] = 0;
    if (tid == 0) lcnt = 0;
    __syncthreads();
    const float* S = scores + (size_t)img * RR * SROW;
    int e0 = blk * P0E;
    int e1 = e0 + P0E; if (e1 > NELEM) e1 = NELEM;
    for (int e = e0 + tid; e < e1; e += 256) {
        int r = e / KK, c = e - r * KK;
        float s = S[(size_t)r * SROW + c];
        if (s > 0.05f) {
            u64 key = ((u64)(~__float_as_uint(s)) << 32) | (u32)e;
            u32 cb = (u32)(key >> 48) - CBASE;
            if (cb > CBINS - 1u) cb = CBINS - 1u;   // unreachable for s in (0.05,1]
            atomicAdd(&lh[cb], 1u);
            u32 p = atomicAdd(&lcnt, 1u);
            if (p < BUFCAP) lbuf[p] = key;
        }
    }
    __syncthreads();
    // partial hist -> hist[img*64K + blk*1024 ..] (64*1024 = full region, no atomics)
    u32* hp = (u32*)(wsb + OFF_HIST) + (size_t)img * HIST_BINS + blk * CBINS;
    for (int b = tid; b < CBINS; b += 256) hp[b] = lh[b];
    if (tid == 0) {
        u32 add = lcnt;
        if (lcnt > BUFCAP) add = CAP2 + 1;  // unreachable; forces fallback if ever hit
        lbase = add ? atomicAdd(&((u32*)(wsb + OFF_STATE + ST_CCNT))[img], add) : 0u;
    }
    __syncthreads();
    u32 n = (lcnt < (u32)BUFCAP) ? lcnt : (u32)BUFCAP;
    u32 base = lbase;
    u64* cand = (u64*)(wsb + OFF_CAND) + (size_t)img * CAP2;
    for (u32 i = tid; i < n; i += 256) {
        u32 pos = base + i;
        if (pos < CAP2) cand[pos] = lbuf[i];
    }
}

// Pass-0 pick: reduce 64 partial hists (coalesced uint4), scan 1024 bins,
// select boundary bin, zero the whole 64K region for pass 1.
__global__ void k_pick0(char* wsb) {
    int img = blockIdx.x; int tid = threadIdx.x;
    __shared__ u32 sv[256];
    __shared__ int sFin;
    u32* h = (u32*)(wsb + OFF_HIST) + (size_t)img * HIST_BINS;
    // thread t owns contiguous compressed bins [4t, 4t+4)
    uint4 r4 = make_uint4(0, 0, 0, 0);
    for (int pb = 0; pb < P0B; ++pb) {
        uint4 v = *(const uint4*)(h + pb * CBINS + 4 * tid);
        r4.x += v.x; r4.y += v.y; r4.z += v.z; r4.w += v.w;
    }
    u32 cs = r4.x + r4.y + r4.z + r4.w;
    sv[tid] = cs;
    __syncthreads();
    for (int off = 1; off < 256; off <<= 1) {
        u32 a = (tid >= off) ? sv[tid - off] : 0;
        __syncthreads();
        sv[tid] += a;
        __syncthreads();
    }
    u32 incl = sv[tid], excl = incl - cs, total = sv[255];
    if (tid == 0) {
        sFin = 0;
        ((u32*)(wsb + OFF_STATE + ST_C))[img] = total;
        if (total <= MPRE) {   // fewer than 2048 candidates: take all
            ((u32*)(wsb + OFF_STATE + ST_DONE))[img] = 1;
            ((u32*)(wsb + OFF_STATE + ST_SHIFT))[img] = 0;
            ((u64*)(wsb + OFF_STATE + ST_PREFIX))[img] = ~0ull;
            sFin = 1;
        }
    }
    __syncthreads();
    u32 need = MPRE;
    if (!sFin && excl < need && incl >= need) {   // boundary in this thread's 4 bins
        u32 arr[4] = { r4.x, r4.y, r4.z, r4.w };
        u32 cum = excl, cntb = 0, rem = 0; int k = 0;
        for (k = 0; k < 4; ++k) {
            if (cum + arr[k] >= need) { cntb = arr[k]; rem = need - cum; break; }
            cum += arr[k];
        }
        u32 bsel = CBASE + (u32)(4 * tid + k);
        ((u64*)(wsb + OFF_STATE + ST_PREFIX))[img] = (u64)bsel;
        ((u32*)(wsb + OFF_STATE + ST_SHIFT))[img] = 48;
        ((u32*)(wsb + OFF_STATE + ST_NEED))[img] = rem;
        if (rem == cntb) ((u32*)(wsb + OFF_STATE + ST_DONE))[img] = 1;
    }
    __syncthreads();
    for (int b = tid; b < HIST_BINS; b += 256) h[b] = 0;   // clean for pass 1
}

// Passes 1..3: histogram over the compact list (or full-scan fallback).
__global__ void k_histN(int p, const float* __restrict__ scores, char* wsb) {
    int img = blockIdx.x / BPI, blk = blockIdx.x % BPI;
    if (((const u32*)(wsb + OFF_STATE + ST_DONE))[img]) return;
    u32 sh = ((const u32*)(wsb + OFF_STATE + ST_SHIFT))[img];
    u64 P  = ((const u64*)(wsb + OFF_STATE + ST_PREFIX))[img];
    u32 ccnt = ((const u32*)(wsb + OFF_STATE + ST_CCNT))[img];
    u32* hist = (u32*)(wsb + OFF_HIST) + (size_t)img * HIST_BINS;
    int binshift = 48 - 16 * p;
    if (ccnt <= CAP2) {
        if (blk >= (int)(CAP2 / 2048)) return;
        const u64* cand = (const u64*)(wsb + OFF_CAND) + (size_t)img * CAP2;
        for (int t = 0; t < 8; ++t) {
            u32 idx = (u32)(blk * 2048 + t * 256 + (int)threadIdx.x);
            if (idx < ccnt) {
                u64 key = cand[idx];
                if ((key >> sh) == P)
                    atomicAdd(&hist[(u32)((key >> binshift) & 0xFFFFull)], 1u);
            }
        }
    } else {   // fallback: full rescan (correctness-identical)
        const float* S = scores + (size_t)img * RR * SROW;
        for (int t = 0; t < 8; ++t) {
            int e = blk * 2048 + t * 256 + (int)threadIdx.x;
            if (e < NELEM) {
                int r = e / KK, c = e - r * KK;
                float s = S[(size_t)r * SROW + c];
                if (s > 0.05f) {
                    u64 key = ((u64)(~__float_as_uint(s)) << 32) | (u32)e;
                    if ((key >> sh) == P)
                        atomicAdd(&hist[(u32)((key >> binshift) & 0xFFFFull)], 1u);
                }
            }
        }
    }
}

// Per-image bin selection for passes 1..3 (64K-bin hist, two 256-wide scans).
// Defensive: if no thread owns the boundary (inconsistent state), mark done
// instead of reading uninitialized LDS (the round-6 fault class).
__global__ void k_pick(int p, char* wsb) {
    int img = blockIdx.x; int tid = threadIdx.x;
    u32* done = (u32*)(wsb + OFF_STATE + ST_DONE);
    __shared__ u32 sdone;
    __shared__ u32 sv[256];
    __shared__ u32 sC[256];
    __shared__ u32 sSel[2];
    if (tid == 0) { sdone = done[img]; sSel[0] = 0xFFFFFFFFu; }
    __syncthreads();
    if (sdone) return;
    u32* h = (u32*)(wsb + OFF_HIST) + (size_t)img * HIST_BINS;
    u32 cs = 0; int b0 = tid * 256;
    for (int b = 0; b < 256; ++b) cs += h[b0 + b];
    sC[tid] = cs; sv[tid] = cs;
    __syncthreads();
    for (int off = 1; off < 256; off <<= 1) {
        u32 add = (tid >= off) ? sv[tid - off] : 0;
        __syncthreads();
        sv[tid] += add;
        __syncthreads();
    }
    u32 incl = sv[tid];
    u32 excl = incl - sC[tid];
    u32 need = ((const u32*)(wsb + OFF_STATE + ST_NEED))[img];
    if (excl < need && incl >= need) { sSel[0] = (u32)tid; sSel[1] = excl; }
    __syncthreads();
    if (sSel[0] == 0xFFFFFFFFu) {      // no boundary: inconsistent, fail safe
        if (tid == 0) done[img] = 1;
    } else {
        int ck = (int)sSel[0]; u32 cum = sSel[1];
        u32 hb = h[ck * 256 + tid];
        sC[tid] = hb; sv[tid] = hb;
        __syncthreads();
        for (int off = 1; off < 256; off <<= 1) {
            u32 add = (tid >= off) ? sv[tid - off] : 0;
            __syncthreads();
            sv[tid] += add;
            __syncthreads();
        }
        u32 need2 = need - cum;
        u32 incl2 = sv[tid];
        u32 excl2 = incl2 - sC[tid];
        if (excl2 < need2 && incl2 >= need2) {   // this thread owns the boundary bin
            int bsel = ck * 256 + tid;
            u32 cntb = sC[tid];
            u32 rem  = need2 - excl2;
            u64* prefA = (u64*)(wsb + OFF_STATE + ST_PREFIX);
            u64 P = (prefA[img] << 16) | (u32)bsel;
            prefA[img] = P;
            ((u32*)(wsb + OFF_STATE + ST_SHIFT))[img] = (u32)(48 - 16 * p);
            ((u32*)(wsb + OFF_STATE + ST_NEED))[img] = rem;
            if (rem == cntb || p == 3) done[img] = 1;
        }
        __syncthreads();
    }
    for (int b = tid; b < HIST_BINS; b += 256) h[b] = 0;
}

// Gather exactly min(C,2048) keys with (key>>shift) <= prefix, compact or fallback.
// Two-phase LDS buffer, one global atomicAdd per block.
__global__ void k_gather(const float* __restrict__ scores, char* wsb) {
    int img = blockIdx.x / BPI, blk = blockIdx.x % BPI;
    u32 sh = ((const u32*)(wsb + OFF_STATE + ST_SHIFT))[img];
    u64 P  = ((const u64*)(wsb + OFF_STATE + ST_PREFIX))[img];
    u32 ccnt = ((const u32*)(wsb + OFF_STATE + ST_CCNT))[img];
    __shared__ u64 lbuf[2048];
    __shared__ u32 lcnt, lbase;
    if (threadIdx.x == 0) lcnt = 0;
    __syncthreads();
    bool compact = (ccnt <= CAP2);
    if (compact) {
        if (blk < (int)(CAP2 / 2048)) {
            const u64* cand = (const u64*)(wsb + OFF_CAND) + (size_t)img * CAP2;
            for (int t = 0; t < 8; ++t) {
                u32 idx = (u32)(blk * 2048 + t * 256 + (int)threadIdx.x);
                if (idx < ccnt) {
                    u64 key = cand[idx];
                    if ((key >> sh) <= P) {
                        u32 p = atomicAdd(&lcnt, 1u);
                        lbuf[p] = key;
                    }
                }
            }
        }
    } else {
        const float* S = scores + (size_t)img * RR * SROW;
        for (int t = 0; t < 8; ++t) {
            int e = blk * 2048 + t * 256 + (int)threadIdx.x;
            if (e < NELEM) {
                int r = e / KK, c = e - r * KK;
                float s = S[(size_t)r * SROW + c];
                if (s > 0.05f) {
                    u64 key = ((u64)(~__float_as_uint(s)) << 32) | (u32)e;
                    if ((key >> sh) <= P) {
                        u32 p = atomicAdd(&lcnt, 1u);
                        lbuf[p] = key;
                    }
                }
            }
        }
    }
    __syncthreads();
    if (threadIdx.x == 0)
        lbase = (lcnt > 0) ? atomicAdd(GCNT_PTR(wsb, img), lcnt) : 0u;
    __syncthreads();
    u32 n = lcnt, base = lbase;
    u64* selk = (u64*)(wsb + OFF_SELK) + (size_t)img * MPRE;
    for (u32 i = threadIdx.x; i < n; i += 256) {
        u32 pos = base + i;
        if (pos < MPRE) selk[pos] = lbuf[i];
    }
}

// Bitonic sort 2048 keys in LDS, decode candidates (clip, class-offset, area).
__global__ __launch_bounds__(1024) void k_sortdec(const float* __restrict__ boxes, char* wsb) {
    int img = blockIdx.x; int tid = threadIdx.x;
    __shared__ u64 sk[MPRE];
    u32 scnt = *GCNT_PTR(wsb, img);
    if (scnt > MPRE) scnt = MPRE;
    const u64* selk = (const u64*)(wsb + OFF_SELK) + (size_t)img * MPRE;
    for (int i = tid; i < MPRE; i += 1024) sk[i] = (i < (int)scnt) ? selk[i] : ~0ull;
    for (u32 k2 = 2; k2 <= MPRE; k2 <<= 1) {
        for (u32 j = k2 >> 1; j > 0; j >>= 1) {
            __syncthreads();
            for (int i = tid; i < MPRE; i += 1024) {
                int ixj = i ^ (int)j;
                if (ixj > i) {
                    u64 a = sk[i], b = sk[ixj];
                    bool up = ((i & (int)k2) == 0);
                    if ((a > b) == up) { sk[i] = b; sk[ixj] = a; }
                }
            }
        }
    }
    __syncthreads();
    float4* cb   = (float4*)(wsb + OFF_CB)   + (size_t)img * MPRE;
    float4* ob   = (float4*)(wsb + OFF_OB)   + (size_t)img * MPRE;
    float*  area = (float*)(wsb + OFF_AREA)  + (size_t)img * MPRE;
    float*  scv  = (float*)(wsb + OFF_SCORE) + (size_t)img * MPRE;
    u32*    flv  = (u32*)(wsb + OFF_FLAT)    + (size_t)img * MPRE;
    for (int i = tid; i < MPRE; i += 1024) {
        if (i < (int)scnt) {
            u64 key = sk[i];
            u32 e = (u32)key;
            u32 sbits = ~((u32)(key >> 32));
            float sc = __uint_as_float(sbits);
            u32 r = e / KK, c = e - r * KK;
            const float* bp = boxes + (((size_t)img * RR + r) * KK + c) * 4;
            float x1 = fminf(fmaxf(bp[0], 0.0f), 1333.0f);
            float y1 = fminf(fmaxf(bp[1], 0.0f), 800.0f);
            float x2 = fminf(fmaxf(bp[2], 0.0f), 1333.0f);
            float y2 = fminf(fmaxf(bp[3], 0.0f), 800.0f);
            float coff = (float)c * 4096.0f;
            float ox1 = __fadd_rn(x1, coff), oy1 = __fadd_rn(y1, coff);
            float ox2 = __fadd_rn(x2, coff), oy2 = __fadd_rn(y2, coff);
            float ar = __fmul_rn(fmaxf(__fsub_rn(ox2, ox1), 0.0f),
                                 fmaxf(__fsub_rn(oy2, oy1), 0.0f));
            cb[i] = make_float4(x1, y1, x2, y2);
            ob[i] = make_float4(ox1, oy1, ox2, oy2);
            area[i] = ar; scv[i] = sc; flv[i] = e;
        } else {
            cb[i] = make_float4(0.f, 0.f, 0.f, 0.f);
            ob[i] = make_float4(0.f, 0.f, 0.f, 0.f);
            area[i] = 0.f; scv[i] = 0.f; flv[i] = 0u;
        }
    }
    if (tid == 0) ((u32*)(wsb + OFF_STATE + ST_CSEL))[img] = scnt;
}

// 8 rows per 512-thread block (one wave per row); box table staged once in LDS.
// IoU vs all 2048 columns -> 32 u64 ballot words, j>i baked in.
__global__ __launch_bounds__(512) void k_iou(char* wsb) {
    int blk = blockIdx.x;                 // 2048 blocks
    int img = blk >> 8; int row0 = (blk & 255) * 8;
    int tid = threadIdx.x;
    __shared__ float4 sob[MPRE];
    __shared__ float  sarea[MPRE];
    const float4* ob   = (const float4*)(wsb + OFF_OB)  + (size_t)img * MPRE;
    const float*  area = (const float*)(wsb + OFF_AREA) + (size_t)img * MPRE;
    for (int i = tid; i < MPRE; i += 512) { sob[i] = ob[i]; sarea[i] = area[i]; }
    __syncthreads();
    int wid = tid >> 6, lane = tid & 63;
    int i = row0 + wid;
    float4 bi = sob[i]; float ai = sarea[i];
    u64* row = (u64*)(wsb + OFF_SUP) + ((size_t)img * MPRE + i) * 32;
    for (int ch = 0; ch < 32; ++ch) {
        int j = ch * 64 + lane;
        float4 bj = sob[j]; float aj = sarea[j];
        float ltx = fmaxf(bi.x, bj.x), lty = fmaxf(bi.y, bj.y);
        float rbx = fminf(bi.z, bj.z), rby = fminf(bi.w, bj.w);
        float w = fmaxf(__fsub_rn(rbx, ltx), 0.0f);
        float h = fmaxf(__fsub_rn(rby, lty), 0.0f);
        float inter = __fmul_rn(w, h);
        float den = __fadd_rn(__fsub_rn(__fadd_rn(ai, aj), inter), 1e-9f);
        float iou = inter / den;
        bool pred = (iou > 0.5f) && (j > i);
        u64 m = __ballot(pred);
        if (lane == 0) row[ch] = m;
    }
}

// Greedy sequential NMS, one wave/image. Lanes 0..31 own suppression words.
// bcur = lane-uniform copy of the word being scanned; early exit at 100 keeps
// (suppression flows strictly forward, ranks >= 100 are ignored by k_out).
__global__ void k_nms(char* wsb) {
    int img = blockIdx.x; int lane = threadIdx.x;
    int csel = (int)((const u32*)(wsb + OFF_STATE + ST_CSEL))[img];
    const u64* S = (const u64*)(wsb + OFF_SUP) + (size_t)img * MPRE * 32;
    u64 supw = 0;
    u64 bcur = 0;
    int kcnt = 0;
    bool doneF = false;
    const int D = 16;
    u64 pre[D]; u64 preb[D];
#pragma unroll
    for (int d = 0; d < D; ++d) {
        pre[d]  = (lane < 32 && d < csel) ? S[(size_t)d * 32 + lane] : 0ull;
        preb[d] = (d < csel) ? S[(size_t)d * 32 + 0] : 0ull;
    }
    for (int base = 0; base < csel && !doneF; base += D) {
        int w = base >> 6;
        if ((base & 63) == 0) bcur = __shfl(supw, w);
        int wn = (base + D) >> 6;
#pragma unroll
        for (int d = 0; d < D; ++d) {
            int i = base + d;
            u64 rowl = pre[d]; u64 rowb = preb[d];
            int ip = i + D;
            pre[d]  = (lane < 32 && ip < csel) ? S[(size_t)ip * 32 + lane] : 0ull;
            preb[d] = (ip < csel) ? S[(size_t)ip * 32 + wn] : 0ull;
            if (i < csel && !doneF) {
                bool kept = !((bcur >> (i & 63)) & 1ull);
                if (kept) {
                    if (lane < 32) supw |= rowl;
                    bcur |= rowb;
                    if (++kcnt >= NTOP) doneF = true;
                }
            }
        }
    }
    if (lane < 32) {
        int b = lane << 6; u64 vw;
        if (csel >= b + 64) vw = ~0ull;
        else if (csel <= b) vw = 0ull;
        else vw = (1ull << (csel - b)) - 1ull;
        ((u64*)(wsb + OFF_KEEP))[img * 32 + lane] = vw & ~supw;
    }
}

// Rank kept candidates, gather rows [cb(4), score, logits(80)], zero the rest.
__global__ void k_out(const float* __restrict__ logits, char* wsb, float* __restrict__ out) {
    int img = blockIdx.x; int tid = threadIdx.x;
    __shared__ u64 kw[32];
    __shared__ u32 kpre[33];
    __shared__ int sel[NTOP];
    __shared__ int snk;
    if (tid < 32) kw[tid] = ((const u64*)(wsb + OFF_KEEP))[img * 32 + tid];
    __syncthreads();
    if (tid == 0) {
        u32 cum = 0;
        for (int w = 0; w < 32; ++w) { kpre[w] = cum; cum += (u32)__popcll(kw[w]); }
        kpre[32] = cum;
        snk = (cum < NTOP) ? (int)cum : NTOP;
    }
    __syncthreads();
    for (int i = tid; i < MPRE; i += 256) {
        u64 w = kw[i >> 6];
        if ((w >> (i & 63)) & 1ull) {
            u32 rank = kpre[i >> 6] + (u32)__popcll(w & ((1ull << (i & 63)) - 1ull));
            if (rank < NTOP) sel[rank] = i;
        }
    }
    __syncthreads();
    int nk = snk;
    const float4* cb  = (const float4*)(wsb + OFF_CB)   + (size_t)img * MPRE;
    const float*  scv = (const float*)(wsb + OFF_SCORE) + (size_t)img * MPRE;
    const u32*    flv = (const u32*)(wsb + OFF_FLAT)    + (size_t)img * MPRE;
    for (int idx = tid; idx < NTOP * 85; idx += 256) {
        int row = idx / 85, col = idx - row * 85;
        float v = 0.0f;
        if (row < nk) {
            int i = sel[row];
            if (col < 4) {
                float4 b = cb[i];
                v = (col == 0) ? b.x : (col == 1) ? b.y : (col == 2) ? b.z : b.w;
            } else if (col == 4) {
                v = scv[i];
            } else {
                u32 e = flv[i]; u32 r = e / KK;
                v = logits[((size_t)img * RR + r) * SROW + (u32)(col - 5)];
            }
        }
        out[(size_t)img * (NTOP * 85) + idx] = v;
    }
}

extern "C" void kernel_launch(void* const* d_in, const int* in_sizes, int n_in,
                              void* d_out, int out_size, void* d_ws, size_t ws_size,
                              hipStream_t stream) {
    const float* boxes  = (const float*)d_in[0];
    const float* scores = (const float*)d_in[1];
    const float* logits = (const float*)d_in[2];
    float* out = (float*)d_out;
    char* wsb = (char*)d_ws;

    int init_blocks = (int)((OFF_SELK / 4 + 255) / 256);
    k_init<<<init_blocks, 256, 0, stream>>>((u32*)d_ws);
    k_hist0<<<NIMG * P0B, 256, 0, stream>>>(scores, wsb);
    k_pick0<<<NIMG, 256, 0, stream>>>(wsb);
    for (int p = 1; p < 4; ++p) {
        k_histN<<<NIMG * BPI, 256, 0, stream>>>(p, scores, wsb);
        k_pick<<<NIMG, 256, 0, stream>>>(p, wsb);
    }
    k_gather<<<NIMG * BPI, 256, 0, stream>>>(scores, wsb);
    k_sortdec<<<NIMG, 1024, 0, stream>>>(boxes, wsb);
    k_iou<<<NIMG * 256, 512, 0, stream>>>(wsb);
    k_nms<<<NIMG, 64, 0, stream>>>(wsb);
    k_out<<<NIMG, 256, 0, stream>>>(logits, wsb, out);
}